// Round 4
// baseline (224.493 us; speedup 1.0000x reference)
//
#include <hip/hip_runtime.h>
#include <math.h>

#define B_   4
#define NQ_  300
#define DIM_ 256
#define H_   8
#define HD_  32
#define N_   4096

typedef _Float16 f16;
typedef f16   f16x8 __attribute__((ext_vector_type(8)));
typedef f16   f16x4 __attribute__((ext_vector_type(4)));
typedef float f32x4 __attribute__((ext_vector_type(4)));

// ---------------------------------------------------------------------------
// Weight prep: WT[z][n][k] = W_z[k][n] * (z==0 ? qscale : 1), f16.
// ---------------------------------------------------------------------------
__global__ __launch_bounds__(256) void prep_wt(
    const float* __restrict__ Wq, const float* __restrict__ Wk,
    const float* __restrict__ Wv, const float* __restrict__ Wp,
    f16* __restrict__ WT, float qscale)
{
  __shared__ float t[64][65];
  const int z = blockIdx.z;
  const float* W = z == 0 ? Wq : z == 1 ? Wk : z == 2 ? Wv : Wp;
  const float s = z == 0 ? qscale : 1.0f;
  f16* O = WT + (size_t)z * 65536;
  const int k0 = blockIdx.y * 64, n0 = blockIdx.x * 64;
  const int r = threadIdx.x >> 2, c0 = (threadIdx.x & 3) * 16;
#pragma unroll
  for (int c = 0; c < 16; c += 4) {
    float4 v = *(const float4*)(W + (size_t)(k0 + r) * 256 + n0 + c0 + c);
    t[r][c0 + c] = v.x; t[r][c0 + c + 1] = v.y;
    t[r][c0 + c + 2] = v.z; t[r][c0 + c + 3] = v.w;
  }
  __syncthreads();
  f16* orow = O + (size_t)(n0 + r) * 256 + k0 + c0;
#pragma unroll
  for (int c = 0; c < 16; c += 4) {
    f16x4 p;
    p[0] = (f16)(t[c0 + c + 0][r] * s);
    p[1] = (f16)(t[c0 + c + 1][r] * s);
    p[2] = (f16)(t[c0 + c + 2][r] * s);
    p[3] = (f16)(t[c0 + c + 3][r] * s);
    *(f16x4*)(orow + c) = p;
  }
}

// ---------------------------------------------------------------------------
// MFMA GEMM body: C = A @ (WT^T) + bias*scale.  WT is [n][k] f16.
// mode 0: fp32 row-major out; 1: f16 row-major; 2: f16 [b][c=n][nk=m&4095].
// ---------------------------------------------------------------------------
__device__ __forceinline__ void gemm_body(
    const void* __restrict__ Ain, const f16* __restrict__ WT,
    const float* __restrict__ bias, void* __restrict__ C,
    int M, float scale, int a_f16, int mode, int bm, int bn, int tid)
{
  __shared__ f16 As[64][40];
  __shared__ f16 Bs[64][40];
  const int lane = tid & 63;
  const int wv = tid >> 6;
  const int l15 = lane & 15, g = lane >> 4;
  const int arow = tid >> 2, akq = (tid & 3) * 8;

  f32x4 acc[4];
#pragma unroll
  for (int nt = 0; nt < 4; ++nt) acc[nt] = (f32x4){0.f, 0.f, 0.f, 0.f};

  for (int k0 = 0; k0 < 256; k0 += 32) {
    {
      const int gm = bm + arow;
      f16x8 av;
      if (gm < M) {
        if (a_f16) {
          av = *(const f16x8*)((const f16*)Ain + (size_t)gm * 256 + k0 + akq);
        } else {
          const float* ap = (const float*)Ain + (size_t)gm * 256 + k0 + akq;
          float4 a0 = *(const float4*)ap;
          float4 a1 = *(const float4*)(ap + 4);
          av[0] = (f16)a0.x; av[1] = (f16)a0.y; av[2] = (f16)a0.z; av[3] = (f16)a0.w;
          av[4] = (f16)a1.x; av[5] = (f16)a1.y; av[6] = (f16)a1.z; av[7] = (f16)a1.w;
        }
      } else {
#pragma unroll
        for (int i = 0; i < 8; ++i) av[i] = (f16)0.f;
      }
      *(f16x8*)&As[arow][akq] = av;
      *(f16x8*)&Bs[arow][akq] =
          *(const f16x8*)(WT + (size_t)(bn + arow) * 256 + k0 + akq);
    }
    __syncthreads();
    const f16x8 af = *(const f16x8*)&As[wv * 16 + l15][g * 8];
#pragma unroll
    for (int nt = 0; nt < 4; ++nt) {
      const f16x8 bf = *(const f16x8*)&Bs[nt * 16 + l15][g * 8];
      acc[nt] = __builtin_amdgcn_mfma_f32_16x16x32_f16(af, bf, acc[nt], 0, 0, 0);
    }
    __syncthreads();
  }

#pragma unroll
  for (int nt = 0; nt < 4; ++nt) {
    const int n = bn + nt * 16 + l15;
    const float bv = bias[n] * scale;
    if (mode == 2) {
      const int m0 = bm + wv * 16 + g * 4;
      const int bb = m0 >> 12, nk = m0 & 4095;
      f16x4 pk;
#pragma unroll
      for (int r = 0; r < 4; ++r) pk[r] = (f16)(acc[nt][r] + bv);
      *(f16x4*)((f16*)C + (size_t)bb * (256 * 4096) + (size_t)n * 4096 + nk) = pk;
    } else {
#pragma unroll
      for (int r = 0; r < 4; ++r) {
        const int m = bm + wv * 16 + g * 4 + r;
        if (m >= M) continue;
        const float v = acc[nt][r] + bv;
        if (mode == 0) ((float*)C)[(size_t)m * 256 + n] = v;
        else           ((f16*)C)[(size_t)m * 256 + n] = (f16)v;
      }
    }
  }
}

// z=0: Q (M=1200), z=1: K, z=2: V  — one launch for all three projections.
__global__ __launch_bounds__(256) void proj_qkv(
    const float* __restrict__ query, const float* __restrict__ kin,
    const float* __restrict__ vin, const f16* __restrict__ WT,
    const float* __restrict__ bq, const float* __restrict__ bk,
    const float* __restrict__ bv, f16* __restrict__ Qf,
    f16* __restrict__ Kf, f16* __restrict__ Vtf, float qscale)
{
  const int z = blockIdx.z;
  const int bm = blockIdx.y * 64, bn = blockIdx.x * 64;
  if (z == 0) {
    if (bm >= B_ * NQ_) return;
    gemm_body(query, WT, bq, Qf, B_ * NQ_, qscale, 0, 1, bm, bn, threadIdx.x);
  } else if (z == 1) {
    gemm_body(kin, WT + 65536, bk, Kf, B_ * N_, 1.0f, 0, 1, bm, bn, threadIdx.x);
  } else {
    gemm_body(vin, WT + 2 * 65536, bv, Vtf, B_ * N_, 1.0f, 0, 2, bm, bn, threadIdx.x);
  }
}

__global__ __launch_bounds__(256) void gemm_out(
    const f16* __restrict__ X, const f16* __restrict__ WT,
    const float* __restrict__ bp, float* __restrict__ out)
{
  gemm_body(X, WT + 3 * 65536, bp, out, B_ * NQ_, 1.0f, 1, 0,
            blockIdx.y * 64, blockIdx.x * 64, threadIdx.x);
}

// ---------------------------------------------------------------------------
// RPE MLP, fp32 (rpe ~±1500; must not round). lane = position j, wave owns a
// 128-wide r-slice; all weight reads wave-uniform -> scalar loads, no LDS.
// ---------------------------------------------------------------------------
__global__ __launch_bounds__(256) void rpe_kernel(
    const float* __restrict__ refpts,
    const float* __restrict__ W1x, const float* __restrict__ b1x, const float* __restrict__ W2x,
    const float* __restrict__ W1y, const float* __restrict__ b1y, const float* __restrict__ W2y,
    float* __restrict__ rpx, float* __restrict__ rpy)
{
  __shared__ float sRed[4][64][8];
  const int tid = threadIdx.x;
  const int lane = tid & 63;
  const int wv = __builtin_amdgcn_readfirstlane(tid >> 6);
  const int bq = blockIdx.x;
  const int axis = blockIdx.y;
  const float* W1 = axis ? W1y : W1x;
  const float* b1 = axis ? b1y : b1x;
  const float* W2 = axis ? W2y : W2x;
  float* out = axis ? rpy : rpx;

  const float c  = refpts[bq * 4 + axis];
  const float sz = refpts[bq * 4 + 2 + axis];
  const float pos = (lane + 0.5f) * 16.0f;
  const float d0 = c - 0.5f * sz - pos;
  const float d1 = c + 0.5f * sz - pos;
  float acc[8] = {};
  const int r0 = wv * 128;
#pragma unroll 4
  for (int i = 0; i < 128; ++i) {
    const int r = r0 + i;
    const float w10 = W1[r], w11 = W1[512 + r], bb = b1[r];
    const float hv = fmaxf(fmaf(d0, w10, fmaf(d1, w11, bb)), 0.0f);
    const float* w2r = W2 + r * 8;
#pragma unroll
    for (int hh = 0; hh < 8; ++hh) acc[hh] += hv * w2r[hh];
  }
#pragma unroll
  for (int hh = 0; hh < 8; ++hh) sRed[wv][lane][hh] = acc[hh];
  __syncthreads();
  for (int idx = tid; idx < 512; idx += 256) {
    const int jj = idx >> 3, hh = idx & 7;
    out[(size_t)bq * 512 + idx] =
        sRed[0][jj][hh] + sRed[1][jj][hh] + sRed[2][jj][hh] + sRed[3][jj][hh];
  }
}

// ---------------------------------------------------------------------------
// MFMA attention. Block = (b,h,32q): two 16-q tiles per wave, 8 waves x 512
// keys. Per 64-key sub-pass: batch-load 4 K-chunks + 8 V-frags into register
// arrays (12 loads in flight), then QK MFMA + score fixup (both q-tiles share
// each K load), one cross-lane max/rescale, then exp2 + 4 PV MFMAs per chunk.
// Exact online softmax in log2 domain; 8 partials merged through LDS.
// __launch_bounds__(512,4): cap VGPR<=128 so 2 blocks/CU co-reside (LDS is
// 64.3KB/block, fits 2 in 160KB) — grid is 320 blocks on 256 CUs, and the
// 12-VMEM scattered inner loop needs >2 waves/SIMD of latency hiding.
// ---------------------------------------------------------------------------
__global__ __launch_bounds__(512, 4) void attn_mfma(
    const f16* __restrict__ Qf, const f16* __restrict__ Kf,
    const f16* __restrict__ Vtf, const float* __restrict__ rpx,
    const float* __restrict__ rpy, const int* __restrict__ mask,
    f16* __restrict__ X)
{
  __shared__ float smask[N_];          // -100*log2e*mask
  __shared__ float srx[32][68];        // rpe_x * log2e
  __shared__ float sry[32][68];        // rpe_y * log2e
  __shared__ float mO[7][2][8][64];
  __shared__ float mlm[7][32];
  __shared__ float mll[7][32];

  const int tid = threadIdx.x;
  const int lane = tid & 63;
  const int kh = tid >> 6;
  const int qg = blockIdx.x % 10;
  const int h  = (blockIdx.x / 10) % H_;
  const int b  = blockIdx.x / (10 * H_);
  const int q0 = qg * 32;
  const float L2E = 1.44269504f;

  {
    const int4* mm4 = (const int4*)(mask + b * N_);
    for (int i = tid; i < N_ / 4; i += 512) {
      int4 mm = mm4[i];
      smask[4 * i + 0] = -100.f * L2E * (float)mm.x;
      smask[4 * i + 1] = -100.f * L2E * (float)mm.y;
      smask[4 * i + 2] = -100.f * L2E * (float)mm.z;
      smask[4 * i + 3] = -100.f * L2E * (float)mm.w;
    }
  }
  for (int i = tid; i < 2048; i += 512) {
    int qq = i >> 6, j = i & 63;
    int qg2 = q0 + qq; if (qg2 > NQ_ - 1) qg2 = NQ_ - 1;
    size_t base = (size_t)(b * NQ_ + qg2) * 512 + (size_t)j * 8 + h;
    srx[qq][j] = rpx[base] * L2E;
    sry[qq][j] = rpy[base] * L2E;
  }
  __syncthreads();

  const int l15 = lane & 15, g = lane >> 4;
  const int qrow0 = q0 + l15;
  const int qrow1 = q0 + 16 + l15;
  const int qa = qrow0 > NQ_ - 1 ? NQ_ - 1 : qrow0;
  const int qbq = qrow1 > NQ_ - 1 ? NQ_ - 1 : qrow1;

  const f16x8 qf0 = *(const f16x8*)(Qf + (size_t)(b * NQ_ + qa) * 256 + h * 32 + g * 8);
  const f16x8 qf1 = *(const f16x8*)(Qf + (size_t)(b * NQ_ + qbq) * 256 + h * 32 + g * 8);

  f32x4 O00 = {0.f,0.f,0.f,0.f}, O01 = {0.f,0.f,0.f,0.f};
  f32x4 O10 = {0.f,0.f,0.f,0.f}, O11 = {0.f,0.f,0.f,0.f};
  float lacc0 = 0.f, lacc1 = 0.f;
  float mrun0 = -1e30f, mrun1 = -1e30f;
  const f16* kb  = Kf + (size_t)b * N_ * 256 + h * 32 + g * 8;
  const f16* v0p = Vtf + (size_t)(b * 256 + h * 32 + l15) * N_ + g * 4;
  const f16* v1p = v0p + (size_t)16 * N_;

  for (int sp = 0; sp < 8; ++sp) {
    const int kbase = kh * 512 + sp * 64;
    // ---- batch loads: 12 VMEM in flight ----
    f16x8 kf[4];
    f16x4 va[4], vb[4];
#pragma unroll
    for (int cc = 0; cc < 4; ++cc) {
      kf[cc] = *(const f16x8*)(kb + (size_t)(kbase + cc * 16 + l15) * 256);
      va[cc] = *(const f16x4*)(v0p + kbase + cc * 16);
      vb[cc] = *(const f16x4*)(v1p + kbase + cc * 16);
    }
    // ---- pass A: QK + fixup (both q-tiles per K chunk) ----
    f32x4 s0[4], s1[4];
    float lm0 = -1e30f, lm1 = -1e30f;
#pragma unroll
    for (int cc = 0; cc < 4; ++cc) {
      const int k0 = kbase + cc * 16;
      f32x4 S0 = __builtin_amdgcn_mfma_f32_16x16x32_f16(
          kf[cc], qf0, (f32x4){0.f,0.f,0.f,0.f}, 0, 0, 0);
      f32x4 S1 = __builtin_amdgcn_mfma_f32_16x16x32_f16(
          kf[cc], qf1, (f32x4){0.f,0.f,0.f,0.f}, 0, 0, 0);
      const float ry0 = sry[l15][k0 >> 6];
      const float ry1 = sry[16 + l15][k0 >> 6];
      const float4 rx0 = *(const float4*)&srx[l15][(k0 & 63) + g * 4];
      const float4 rx1 = *(const float4*)&srx[16 + l15][(k0 & 63) + g * 4];
      const float4 sm = *(const float4*)&smask[k0 + g * 4];
      s0[cc][0] = fmaf(S0[0], L2E, rx0.x + sm.x + ry0);
      s0[cc][1] = fmaf(S0[1], L2E, rx0.y + sm.y + ry0);
      s0[cc][2] = fmaf(S0[2], L2E, rx0.z + sm.z + ry0);
      s0[cc][3] = fmaf(S0[3], L2E, rx0.w + sm.w + ry0);
      s1[cc][0] = fmaf(S1[0], L2E, rx1.x + sm.x + ry1);
      s1[cc][1] = fmaf(S1[1], L2E, rx1.y + sm.y + ry1);
      s1[cc][2] = fmaf(S1[2], L2E, rx1.z + sm.z + ry1);
      s1[cc][3] = fmaf(S1[3], L2E, rx1.w + sm.w + ry1);
      lm0 = fmaxf(lm0, fmaxf(fmaxf(s0[cc][0], s0[cc][1]), fmaxf(s0[cc][2], s0[cc][3])));
      lm1 = fmaxf(lm1, fmaxf(fmaxf(s1[cc][0], s1[cc][1]), fmaxf(s1[cc][2], s1[cc][3])));
    }
    lm0 = fmaxf(lm0, __shfl_xor(lm0, 16));
    lm0 = fmaxf(lm0, __shfl_xor(lm0, 32));
    lm1 = fmaxf(lm1, __shfl_xor(lm1, 16));
    lm1 = fmaxf(lm1, __shfl_xor(lm1, 32));
    const float mn0 = fmaxf(mrun0, lm0);
    const float mn1 = fmaxf(mrun1, lm1);
    const float f0 = exp2f(mrun0 - mn0);
    const float f1 = exp2f(mrun1 - mn1);
    mrun0 = mn0; mrun1 = mn1;
    lacc0 *= f0; lacc1 *= f1;
#pragma unroll
    for (int r = 0; r < 4; ++r) {
      O00[r] *= f0; O01[r] *= f0;
      O10[r] *= f1; O11[r] *= f1;
    }
    // ---- pass B: exp2 + PV ----
#pragma unroll
    for (int cc = 0; cc < 4; ++cc) {
      f16x4 pf0, pf1;
#pragma unroll
      for (int r = 0; r < 4; ++r) {
        const float p0 = exp2f(s0[cc][r] - mrun0);
        const float p1 = exp2f(s1[cc][r] - mrun1);
        lacc0 += p0; lacc1 += p1;
        pf0[r] = (f16)p0; pf1[r] = (f16)p1;
      }
      O00 = __builtin_amdgcn_mfma_f32_16x16x16f16(va[cc], pf0, O00, 0, 0, 0);
      O01 = __builtin_amdgcn_mfma_f32_16x16x16f16(vb[cc], pf0, O01, 0, 0, 0);
      O10 = __builtin_amdgcn_mfma_f32_16x16x16f16(va[cc], pf1, O10, 0, 0, 0);
      O11 = __builtin_amdgcn_mfma_f32_16x16x16f16(vb[cc], pf1, O11, 0, 0, 0);
    }
  }

  lacc0 += __shfl_xor(lacc0, 16); lacc0 += __shfl_xor(lacc0, 32);
  lacc1 += __shfl_xor(lacc1, 16); lacc1 += __shfl_xor(lacc1, 32);

  if (kh > 0) {
#pragma unroll
    for (int r = 0; r < 4; ++r) {
      mO[kh - 1][0][r][lane]     = O00[r];
      mO[kh - 1][0][4 + r][lane] = O01[r];
      mO[kh - 1][1][r][lane]     = O10[r];
      mO[kh - 1][1][4 + r][lane] = O11[r];
    }
    if (lane < 16) {
      mlm[kh - 1][lane]      = mrun0;
      mlm[kh - 1][16 + lane] = mrun1;
      mll[kh - 1][lane]      = lacc0;
      mll[kh - 1][16 + lane] = lacc1;
    }
  }
  __syncthreads();
  if (kh == 0) {
#pragma unroll
    for (int qt = 0; qt < 2; ++qt) {
      const float mr = qt ? mrun1 : mrun0;
      const float la = qt ? lacc1 : lacc0;
      const f32x4 Oa = qt ? O10 : O00;
      const f32x4 Ob = qt ? O11 : O01;
      float ms = mr;
#pragma unroll
      for (int w = 0; w < 7; ++w) ms = fmaxf(ms, mlm[w][qt * 16 + l15]);
      const float fme = exp2f(mr - ms);
      float lt = la * fme;
      float fw[7];
#pragma unroll
      for (int w = 0; w < 7; ++w) {
        fw[w] = exp2f(mlm[w][qt * 16 + l15] - ms);
        lt += mll[w][qt * 16 + l15] * fw[w];
      }
      const float rl = 1.0f / lt;
      const int qrow = qt ? qrow1 : qrow0;
      if (qrow < NQ_) {
        f16* xr = X + (size_t)(b * NQ_ + qrow) * 256 + h * 32;
        f16x4 p0, p1;
#pragma unroll
        for (int r = 0; r < 4; ++r) {
          float o0 = Oa[r] * fme, o1 = Ob[r] * fme;
#pragma unroll
          for (int w = 0; w < 7; ++w) {
            o0 += mO[w][qt][r][lane] * fw[w];
            o1 += mO[w][qt][4 + r][lane] * fw[w];
          }
          p0[r] = (f16)(o0 * rl);
          p1[r] = (f16)(o1 * rl);
        }
        *(f16x4*)(xr + g * 4) = p0;
        *(f16x4*)(xr + 16 + g * 4) = p1;
      }
    }
  }
}

// ---------------------------------------------------------------------------
extern "C" void kernel_launch(void* const* d_in, const int* in_sizes, int n_in,
                              void* d_out, int out_size, void* d_ws, size_t ws_size,
                              hipStream_t stream)
{
  const float* query  = (const float*)d_in[0];
  const float* refpts = (const float*)d_in[1];
  const float* kin    = (const float*)d_in[2];
  const float* vin    = (const float*)d_in[3];
  const int*   mask   = (const int*)d_in[5];
  const float* Wq = (const float*)d_in[6];
  const float* bq = (const float*)d_in[7];
  const float* Wk = (const float*)d_in[8];
  const float* bk = (const float*)d_in[9];
  const float* Wv = (const float*)d_in[10];
  const float* bv = (const float*)d_in[11];
  const float* Wp = (const float*)d_in[12];
  const float* bp = (const float*)d_in[13];
  const float* W1x = (const float*)d_in[14];
  const float* b1x = (const float*)d_in[15];
  const float* W2x = (const float*)d_in[16];
  const float* W1y = (const float*)d_in[17];
  const float* b1y = (const float*)d_in[18];
  const float* W2y = (const float*)d_in[19];

  char* wsb = (char*)d_ws;
  f16*   Qf  = (f16*)(wsb);                 // 1216*256 f16   = 622592 B
  f16*   Kf  = (f16*)(wsb + 622592);        // 4*4096*256 f16 = 8388608 B
  f16*   Vtf = (f16*)(wsb + 9011200);       // 4*256*4096 f16 = 8388608 B
  float* rpx = (float*)(wsb + 17399808);    // 4*300*512 f32  = 2457600 B
  float* rpy = (float*)(wsb + 19857408);    // 2457600 B
  f16*   X   = (f16*)(wsb + 22315008);      // 1216*256 f16   = 622592 B
  f16*   WT  = (f16*)(wsb + 22937600);      // 4*256*256 f16  = 524288 B

  const float scale = 0.17677669529663687f;  // 32^-0.5

  hipLaunchKernelGGL(prep_wt, dim3(4, 4, 4), dim3(256), 0, stream,
                     Wq, Wk, Wv, Wp, WT, scale);
  hipLaunchKernelGGL(rpe_kernel, dim3(B_ * NQ_, 2), dim3(256), 0, stream,
                     refpts, W1x, b1x, W2x, W1y, b1y, W2y, rpx, rpy);
  hipLaunchKernelGGL(proj_qkv, dim3(4, 256, 3), dim3(256), 0, stream,
                     query, kin, vin, WT, bq, bk, bv, Qf, Kf, Vtf, scale);
  hipLaunchKernelGGL(attn_mfma, dim3(B_ * H_ * 10), dim3(512), 0, stream,
                     Qf, Kf, Vtf, rpx, rpy, mask, X);
  hipLaunchKernelGGL(gemm_out, dim3(4, 19), dim3(256), 0, stream,
                     X, WT, bp, (float*)d_out);
}